// Round 13
// baseline (370.826 us; speedup 1.0000x reference)
//
#include <hip/hip_runtime.h>
#include <hip/hip_cooperative_groups.h>

namespace cg = cooperative_groups;

// Problem constants (from reference)
#define N_NODES 100000
#define N_EDGES 1600000
#define D_IN    50
#define HIDDEN  128
#define NCLS    8

// Bucket-sort parameters
#define TILE    2048
#define NTILES  ((N_EDGES + TILE - 1) / TILE)   // 782
#define BSHIFT  9
#define NB      196                              // ceil(100000 / 512)

// prep kernel block ranges
#define PREP_CONVX_BLOCKS 12500                  // N_NODES*32 / 256
#define PREP_W_BLOCKS     36                     // 9216 threads

// LDS row stride (dwords) for padded bf16 weight rows: 128 bf16 + 8 pad = 136 bf16
#define LW 68

typedef __bf16 bf16_t;
typedef bf16_t bf16x8 __attribute__((ext_vector_type(8)));
typedef float  f32x4  __attribute__((ext_vector_type(4)));

// ---------------------------------------------------------------------------
// Helpers: bf16 pack/unpack (RNE)
// ---------------------------------------------------------------------------
__device__ __forceinline__ unsigned f2bf(float f) {
    union { float f; unsigned u; } a; a.f = f;
    unsigned u = a.u;
    return (u + 0x7FFFu + ((u >> 16) & 1u)) >> 16;
}
__device__ __forceinline__ unsigned pack2(float a, float b) {
    return f2bf(a) | (f2bf(b) << 16);
}
__device__ __forceinline__ float bf_lo(unsigned v) { return __uint_as_float(v << 16); }
__device__ __forceinline__ float bf_hi(unsigned v) { return __uint_as_float(v & 0xFFFF0000u); }

#define ACC4(a, u) { a[0]+=bf_lo(u.x); a[1]+=bf_hi(u.x); a[2]+=bf_lo(u.y); a[3]+=bf_hi(u.y); \
                     a[4]+=bf_lo(u.z); a[5]+=bf_hi(u.z); a[6]+=bf_lo(u.w); a[7]+=bf_hi(u.w); }

// ===========================================================================
// prep: fused conv_x (xb 128B bf16 rows + Acat x-part) | conv_w.
// ===========================================================================
__global__ __launch_bounds__(256) void prep_kernel(
    const float* __restrict__ x,
    const float* __restrict__ W1l, const float* __restrict__ W1r,
    const float* __restrict__ W2l, const float* __restrict__ W2r,
    unsigned* __restrict__ xb, unsigned* __restrict__ acat,
    unsigned* __restrict__ Wt1g, unsigned* __restrict__ W2tg)
{
    int blk = blockIdx.x;
    int tid = threadIdx.x;

    if (blk < PREP_CONVX_BLOCKS) {
        // ---- conv_x: xb rows padded to 32 dwords (128B, 2 aligned lines) ----
        int t = blk * 256 + tid;
        int n = t >> 5, j = t & 31;
        if (j < 25) {
            float2 v = ((const float2*)x)[n * 25 + j];
            unsigned pk = pack2(v.x, v.y);
            xb[n * 32 + j] = pk;
            acat[(size_t)n * 64 + 25 + j] = pk;
        } else {
            xb[n * 32 + j] = 0u;
            int z = n * 64 + 50 + (j - 25) * 2;
            acat[z] = 0u;
            acat[z + 1] = 0u;
        }
    } else {
        // ---- conv_w ----
        int t = (blk - PREP_CONVX_BLOCKS) * 256 + tid;
        if (t < 8192) {
            int n = t >> 6, kp = t & 63;
            int k0 = kp * 2, k1 = k0 + 1;
            float v0 = (k0 < 50) ? W1l[k0 * 128 + n] : ((k0 < 100) ? W1r[(k0 - 50) * 128 + n] : 0.0f);
            float v1 = (k1 < 50) ? W1l[k1 * 128 + n] : ((k1 < 100) ? W1r[(k1 - 50) * 128 + n] : 0.0f);
            Wt1g[t] = pack2(v0, v1);
        } else if (t < 8192 + 1024) {
            int u = t - 8192;
            int n2 = u >> 6, kp = u & 63;
            int k0 = kp * 2;
            float v0 = (n2 < 8) ? W2l[k0 * 8 + n2] : W2r[k0 * 8 + n2 - 8];
            float v1 = (n2 < 8) ? W2l[(k0 + 1) * 8 + n2] : W2r[(k0 + 1) * 8 + n2 - 8];
            W2tg[u] = pack2(v0, v1);
        }
    }
}

// ===========================================================================
// sort_coop: the whole CSR build in ONE cooperative kernel.
// Grid = NTILES (782) blocks x 256 threads; grid.sync() between phases.
//  A: per-tile bucket histogram -> g_hist[tile][NB]
//  B: per-bucket exclusive scan over tiles (blocks 0..NB-1); btot[b]
//  C: per-tile LDS reorder -> bk_pack (bbase recomputed locally from btot)
//  D: per-bucket degree hist + scan -> offs, cursor scatter -> sorted_src
// ===========================================================================
__global__ __launch_bounds__(256) void sort_coop_kernel(
    const int* __restrict__ src, const int* __restrict__ dst,
    int* __restrict__ g_hist, int* __restrict__ btot,
    unsigned* __restrict__ bk_pack,
    int* __restrict__ sorted_src, int* __restrict__ offs)
{
    cg::grid_group grid = cg::this_grid();
    __shared__ int sm[4112];   // 16448 B, phase-overlaid
    const int blk = blockIdx.x;
    const int tid = threadIdx.x;

    // ---------------- Phase A ----------------
    {
        int* lh = sm;
        for (int i = tid; i < NB; i += 256) lh[i] = 0;
        __syncthreads();
        int base = blk * TILE;
        int cnt = min(TILE, N_EDGES - base);
        for (int i = tid; i < cnt; i += 256)
            atomicAdd(&lh[dst[base + i] >> BSHIFT], 1);
        __syncthreads();
        for (int i = tid; i < NB; i += 256) g_hist[blk * NB + i] = lh[i];
    }
    grid.sync();

    // ---------------- Phase B ----------------
    if (blk < NB) {
        int* s = sm;
        int b = blk;
        int t4 = tid * 4;
        int vloc[4]; int sum = 0;
        #pragma unroll
        for (int k = 0; k < 4; ++k) {
            int t = t4 + k;
            vloc[k] = (t < NTILES) ? g_hist[t * NB + b] : 0;
            sum += vloc[k];
        }
        s[tid] = sum;
        __syncthreads();
        for (int d = 1; d < 256; d <<= 1) {
            int t = (tid >= d) ? s[tid - d] : 0;
            __syncthreads();
            s[tid] += t;
            __syncthreads();
        }
        int ex = s[tid] - sum;
        #pragma unroll
        for (int k = 0; k < 4; ++k) {
            int t = t4 + k;
            if (t < NTILES) g_hist[t * NB + b] = ex;
            ex += vloc[k];
        }
        if (tid == 255) btot[b] = s[255];
    }
    grid.sync();

    // ---------------- Phase C ----------------
    {
        int* hist = sm;                                   // 196
        int* seg  = sm + 196;                             // 196
        int* cur  = sm + 392;                             // 196
        int* gof  = sm + 588;                             // 196
        int* sc   = sm + 784;                             // 256
        unsigned* s_pack = (unsigned*)(sm + 1040);        // 2048
        unsigned short* s_bkt = (unsigned short*)(sm + 3088); // 2048 ushort

        // local bbase (exclusive scan of btot) -> gof
        int vb = (tid < NB) ? btot[tid] : 0;
        sc[tid] = vb;
        __syncthreads();
        for (int d = 1; d < 256; d <<= 1) {
            int t = (tid >= d) ? sc[tid - d] : 0;
            __syncthreads();
            sc[tid] += t;
            __syncthreads();
        }
        int bbase_t = sc[tid] - vb;
        if (tid < NB) gof[tid] = g_hist[blk * NB + tid] + bbase_t;
        for (int i = tid; i < NB; i += 256) hist[i] = 0;
        __syncthreads();

        int base = blk * TILE;
        int cnt = min(TILE, N_EDGES - base);
        int es[8], ed[8];
        #pragma unroll
        for (int k = 0; k < 8; ++k) {
            int i = tid + k * 256;
            if (i < cnt) {
                es[k] = src[base + i];
                ed[k] = dst[base + i];
                atomicAdd(&hist[ed[k] >> BSHIFT], 1);
            }
        }
        __syncthreads();

        int v = (tid < NB) ? hist[tid] : 0;
        sc[tid] = v;
        __syncthreads();
        for (int d = 1; d < 256; d <<= 1) {
            int t = (tid >= d) ? sc[tid - d] : 0;
            __syncthreads();
            sc[tid] += t;
            __syncthreads();
        }
        if (tid < NB) { seg[tid] = sc[tid] - v; cur[tid] = sc[tid] - v; }
        __syncthreads();

        #pragma unroll
        for (int k = 0; k < 8; ++k) {
            int i = tid + k * 256;
            if (i < cnt) {
                int b = ed[k] >> BSHIFT;
                int p = atomicAdd(&cur[b], 1);
                s_pack[p] = (unsigned)es[k] | ((unsigned)(ed[k] & 511) << 17);
                s_bkt[p] = (unsigned short)b;
            }
        }
        __syncthreads();

        for (int i = tid; i < cnt; i += 256) {
            int b = s_bkt[i];
            int g = gof[b] + (i - seg[b]);
            bk_pack[g] = s_pack[i];
        }
    }
    grid.sync();

    // ---------------- Phase D ----------------
    if (blk < NB) {
        int* ldeg = sm;          // 512
        int* s    = sm + 512;    // 256
        int* shr  = sm + 768;    // 1
        int b = blk;

        // local bbase[b]
        int vb = (tid < NB) ? btot[tid] : 0;
        s[tid] = vb;
        __syncthreads();
        for (int d = 1; d < 256; d <<= 1) {
            int t = (tid >= d) ? s[tid - d] : 0;
            __syncthreads();
            s[tid] += t;
            __syncthreads();
        }
        if (tid == b) shr[0] = s[tid] - vb;
        __syncthreads();
        int ebase = shr[0];
        int ecnt = btot[b];
        int nbase = b << BSHIFT;

        ldeg[tid] = 0;
        ldeg[tid + 256] = 0;
        __syncthreads();
        for (int i = tid; i < ecnt; i += 256)
            atomicAdd(&ldeg[bk_pack[ebase + i] >> 17], 1);
        __syncthreads();

        // exclusive scan of 512 degrees with 256 threads (2 per thread)
        int v0 = ldeg[2 * tid], v1 = ldeg[2 * tid + 1];
        int pv = v0 + v1;
        s[tid] = pv;
        __syncthreads();
        for (int d = 1; d < 256; d <<= 1) {
            int t = (tid >= d) ? s[tid - d] : 0;
            __syncthreads();
            s[tid] += t;
            __syncthreads();
        }
        int ex = s[tid] - pv;

        int n0 = nbase + 2 * tid;
        if (n0 < N_NODES)     offs[n0]     = ebase + ex;
        if (n0 + 1 < N_NODES) offs[n0 + 1] = ebase + ex + v0;
        __syncthreads();
        ldeg[2 * tid]     = ex;
        ldeg[2 * tid + 1] = ex + v0;
        __syncthreads();

        for (int i = tid; i < ecnt; i += 256) {
            unsigned pk = bk_pack[ebase + i];
            int p = atomicAdd(&ldeg[pk >> 17], 1);
            sorted_src[ebase + p] = (int)(pk & 0x1FFFFu);
        }
        if (b == 0 && tid == 0) offs[N_NODES] = N_EDGES;
    }
}

// ===========================================================================
// Gather-aggregate bf16 x rows (128B rows, uint4 loads).
// ONE NODE PER WAVE: 8 edge-slots x 8 uint4-lanes, unroll 2.
// ===========================================================================
__global__ __launch_bounds__(256) void agg_x_kernel(
    const uint4* __restrict__ xb4,     // [N][8] uint4
    const int*   __restrict__ offs,
    const int*   __restrict__ ss,
    unsigned* __restrict__ acat)
{
    int node = blockIdx.x * 4 + (threadIdx.x >> 6);
    int lane = threadIdx.x & 63;
    int slot = lane >> 3;     // 0..7 (edge slot)
    int ld   = lane & 7;      // 0..7 (uint4 within 128B row)
    if (node >= N_NODES) return;
    int beg = offs[node], end = offs[node + 1];
    float a0[8] = {0,0,0,0,0,0,0,0};
    float a1[8] = {0,0,0,0,0,0,0,0};
    int i = beg;
    for (; i + 15 < end; i += 16) {
        int s0 = ss[i + slot];
        int s1 = ss[i + slot + 8];
        uint4 u0 = xb4[s0 * 8 + ld];
        uint4 u1 = xb4[s1 * 8 + ld];
        ACC4(a0, u0);
        ACC4(a1, u1);
    }
    for (; i + 7 < end; i += 8) {
        uint4 u = xb4[ss[i + slot] * 8 + ld];
        ACC4(a0, u);
    }
    int rem = end - i;
    if (slot < rem) {
        uint4 u = xb4[ss[i + slot] * 8 + ld];
        ACC4(a1, u);
    }
    float t[8];
    #pragma unroll
    for (int k = 0; k < 8; ++k) {
        float v = a0[k] + a1[k];
        v += __shfl_xor(v, 8);
        v += __shfl_xor(v, 16);
        v += __shfl_xor(v, 32);
        t[k] = v;
    }
    if (slot == 0) {
        float inv = 1.0f / fmaxf((float)(end - beg), 1.0f);
        if (ld < 6) {
            uint4 o;
            o.x = pack2(t[0] * inv, t[1] * inv);
            o.y = pack2(t[2] * inv, t[3] * inv);
            o.z = pack2(t[4] * inv, t[5] * inv);
            o.w = pack2(t[6] * inv, t[7] * inv);
            *((uint4*)(acat + (size_t)node * 64 + ld * 4)) = o;
        } else if (ld == 6) {
            acat[(size_t)node * 64 + 24] = pack2(t[0] * inv, t[1] * inv);
        }
    }
}

// ===========================================================================
// Fused MLP: h = relu(Acat @ W1cat + b1) via MFMA (swapped operands), then
// p = bf16(h@W2l), q = h@W2r + b2 via a second MFMA pass through LDS.
// ===========================================================================
__global__ __launch_bounds__(256) void fused_mlp_kernel(
    const unsigned* __restrict__ Acat,   // [N][64] dwords (128 bf16)
    const unsigned* __restrict__ Wt1g,   // [128][64] dwords
    const unsigned* __restrict__ W2tg,   // [16][64] dwords
    const float* __restrict__ b1,
    const float* __restrict__ b2,
    unsigned* __restrict__ pb,           // [N][4] dwords (8 bf16)
    float* __restrict__ q)               // [N][8]
{
    __shared__ unsigned sWt[128 * LW];
    __shared__ unsigned sW2t[16 * LW];
    __shared__ bf16_t   sH[4][16 * 136];

    int tid = threadIdx.x;
    for (int t = tid; t < 128 * 64; t += 256)
        sWt[(t >> 6) * LW + (t & 63)] = Wt1g[t];
    for (int t = tid; t < 16 * 64; t += 256)
        sW2t[(t >> 6) * LW + (t & 63)] = W2tg[t];
    __syncthreads();

    const int w    = tid >> 6;
    const int lane = tid & 63;
    const int lo   = lane & 15;
    const int g    = lane >> 4;

    float b1v[8][4];
    #pragma unroll
    for (int nt = 0; nt < 8; ++nt)
        #pragma unroll
        for (int r = 0; r < 4; ++r)
            b1v[nt][r] = b1[nt * 16 + g * 4 + r];
    float b2v[4];
    #pragma unroll
    for (int r = 0; r < 4; ++r)
        b2v[r] = (g >= 2) ? b2[(g - 2) * 4 + r] : 0.0f;

    bf16_t* myH = &sH[w][0];

    for (int tile = blockIdx.x; tile * 64 < N_NODES; tile += gridDim.x) {
        int node = tile * 64 + w * 16 + lo;
        int nclamp = min(node, N_NODES - 1);

        int4 bi[4];
        #pragma unroll
        for (int ks = 0; ks < 4; ++ks)
            bi[ks] = *((const int4*)(Acat + (size_t)nclamp * 64 + ks * 16 + g * 4));

        f32x4 acc[8];
        #pragma unroll
        for (int nt = 0; nt < 8; ++nt) acc[nt] = (f32x4)0.0f;
        #pragma unroll
        for (int nt = 0; nt < 8; ++nt) {
            #pragma unroll
            for (int ks = 0; ks < 4; ++ks) {
                int4 ai = *((const int4*)(sWt + (nt * 16 + lo) * LW + ks * 16 + g * 4));
                acc[nt] = __builtin_amdgcn_mfma_f32_16x16x32_bf16(
                    __builtin_bit_cast(bf16x8, ai),
                    __builtin_bit_cast(bf16x8, bi[ks]), acc[nt], 0, 0, 0);
            }
        }

        #pragma unroll
        for (int nt = 0; nt < 8; ++nt) {
            union { bf16_t h[4]; uint2 u; } pk;
            #pragma unroll
            for (int r = 0; r < 4; ++r)
                pk.h[r] = (bf16_t)fmaxf(acc[nt][r] + b1v[nt][r], 0.0f);
            *((uint2*)(myH + lo * 136 + nt * 16 + g * 4)) = pk.u;
        }
        __syncthreads();

        f32x4 acc2 = (f32x4)0.0f;
        #pragma unroll
        for (int ks = 0; ks < 4; ++ks) {
            int4 a2 = *((const int4*)(sW2t + lo * LW + ks * 16 + g * 4));
            int4 h2 = *((const int4*)(myH + lo * 136 + ks * 32 + g * 8));
            acc2 = __builtin_amdgcn_mfma_f32_16x16x32_bf16(
                __builtin_bit_cast(bf16x8, a2),
                __builtin_bit_cast(bf16x8, h2), acc2, 0, 0, 0);
        }

        if (node < N_NODES) {
            if (g < 2) {
                union { bf16_t h[4]; uint2 u; } pk;
                #pragma unroll
                for (int r = 0; r < 4; ++r) pk.h[r] = (bf16_t)acc2[r];
                *((uint2*)(pb + (size_t)node * 4 + g * 2)) = pk.u;
            } else {
                float4 qq;
                qq.x = acc2[0] + b2v[0];
                qq.y = acc2[1] + b2v[1];
                qq.z = acc2[2] + b2v[2];
                qq.w = acc2[3] + b2v[3];
                *((float4*)(q + (size_t)node * 8 + (g - 2) * 4)) = qq;
            }
        }
        __syncthreads();
    }
}

// ===========================================================================
// Gather-aggregate bf16 p rows + final: out = (sum p[src]) / max(deg,1) + q
// ===========================================================================
__global__ __launch_bounds__(256) void aggp_final_kernel(
    const unsigned* __restrict__ pb,   // [N][4] dwords (8 bf16)
    const float*    __restrict__ q,
    const int*      __restrict__ offs,
    const int*      __restrict__ ss,
    float* __restrict__ out)
{
    int node = blockIdx.x * 4 + (threadIdx.x >> 6);
    int lane = threadIdx.x & 63;
    int k  = lane >> 2;
    int c2 = lane & 3;
    if (node >= N_NODES) return;
    int beg = offs[node], end = offs[node + 1];
    float2 acc = make_float2(0.0f, 0.0f);
    int i = beg + k;
    int sNext = (i < end) ? ss[i] : 0;
    for (; i < end; i += 16) {
        int s = sNext;
        int i2 = i + 16;
        sNext = (i2 < end) ? ss[i2] : 0;
        unsigned v = pb[s * 4 + c2];
        acc.x += bf_lo(v);
        acc.y += bf_hi(v);
    }
    acc.x += __shfl_xor(acc.x, 4);  acc.y += __shfl_xor(acc.y, 4);
    acc.x += __shfl_xor(acc.x, 8);  acc.y += __shfl_xor(acc.y, 8);
    acc.x += __shfl_xor(acc.x, 16); acc.y += __shfl_xor(acc.y, 16);
    acc.x += __shfl_xor(acc.x, 32); acc.y += __shfl_xor(acc.y, 32);
    if (lane < 4) {
        float inv = 1.0f / fmaxf((float)(end - beg), 1.0f);
        float2 qq = ((const float2*)(q + (size_t)node * NCLS))[c2];
        ((float2*)(out + (size_t)node * NCLS))[c2] =
            make_float2(acc.x * inv + qq.x, acc.y * inv + qq.y);
    }
}

// ===========================================================================
extern "C" void kernel_launch(void* const* d_in, const int* in_sizes, int n_in,
                              void* d_out, int out_size, void* d_ws, size_t ws_size,
                              hipStream_t stream)
{
    const float* x   = (const float*)d_in[0];
    const int*   ei  = (const int*)  d_in[1];
    const float* W1l = (const float*)d_in[2];
    const float* W1r = (const float*)d_in[3];
    const float* b1  = (const float*)d_in[4];
    const float* W2l = (const float*)d_in[5];
    const float* W2r = (const float*)d_in[6];
    const float* b2  = (const float*)d_in[7];
    float* out = (float*)d_out;

    const int* src = ei;
    const int* dst = ei + N_EDGES;

    // Workspace layout (dword units; all segment sizes are multiples of 4)
    int* ws = (int*)d_ws;
    int*      offs       = ws;                                   // 100004
    int*      g_hist     = offs + (N_NODES + 4);                 // NTILES*NB + pad
    int*      btot       = g_hist + (NTILES * NB + 4);           // 512
    int*      bbase      = btot + 512;                           // 512 (unused now)
    int*      sorted_src = bbase + 512;                          // E
    unsigned* xb         = (unsigned*)(sorted_src + N_EDGES);    // N*32 (128B rows)
    unsigned* Acat       = xb + (size_t)N_NODES * 32;            // N*64
    unsigned* Wt1g       = Acat + (size_t)N_NODES * 64;          // 8192
    unsigned* W2tg       = Wt1g + 8192;                          // 1024
    unsigned* pb         = W2tg + 1024;                          // N*4
    float*    q          = (float*)(pb + (size_t)N_NODES * 4);   // N*8
    unsigned* bk_pack    = (unsigned*)(q + (size_t)N_NODES * 8); // E

    // prep: conv_x | conv_w fused
    prep_kernel<<<PREP_CONVX_BLOCKS + PREP_W_BLOCKS, 256, 0, stream>>>(
        x, W1l, W1r, W2l, W2r, xb, Acat, Wt1g, W2tg);

    // CSR build: single cooperative kernel (phases A-D with grid.sync)
    {
        void* args[] = {
            (void*)&src, (void*)&dst, (void*)&g_hist, (void*)&btot,
            (void*)&bk_pack, (void*)&sorted_src, (void*)&offs
        };
        (void)hipLaunchCooperativeKernel((const void*)sort_coop_kernel,
                                         dim3(NTILES), dim3(256), args, 0, stream);
    }

    // Layer 1 aggregation (writes Acat cols 0..49)
    agg_x_kernel<<<(N_NODES + 3) / 4, 256, 0, stream>>>(
        (const uint4*)xb, offs, sorted_src, Acat);

    // Fused layer1 GEMM + relu + layer2 GEMMs (h stays on-chip)
    fused_mlp_kernel<<<512, 256, 0, stream>>>(Acat, Wt1g, W2tg, b1, b2, pb, q);

    // Layer 2 aggregation + final
    aggp_final_kernel<<<(N_NODES + 3) / 4, 256, 0, stream>>>(
        (const unsigned*)pb, q, offs, sorted_src, out);
}

// Round 14
// 126.582 us; speedup vs baseline: 2.9295x; 2.9295x over previous
//
#include <hip/hip_runtime.h>

// Problem constants (from reference)
#define N_NODES 100000
#define N_EDGES 1600000
#define D_IN    50
#define HIDDEN  128
#define NCLS    8

// Bucket-sort parameters
#define TILE    2048
#define NTILES  ((N_EDGES + TILE - 1) / TILE)   // 782
#define BSHIFT  9
#define NB      196                              // ceil(100000 / 512)

// prep kernel block ranges
#define PREP_CONVX_BLOCKS 12500                  // N_NODES*32 / 256
#define PREP_W_BLOCKS     36                     // 9216 threads

// LDS row stride (dwords) for padded bf16 weight rows: 128 bf16 + 8 pad = 136 bf16
#define LW 68

typedef __bf16 bf16_t;
typedef bf16_t bf16x8 __attribute__((ext_vector_type(8)));
typedef float  f32x4  __attribute__((ext_vector_type(4)));

// ---------------------------------------------------------------------------
// Helpers: bf16 pack/unpack (RNE)
// ---------------------------------------------------------------------------
__device__ __forceinline__ unsigned f2bf(float f) {
    union { float f; unsigned u; } a; a.f = f;
    unsigned u = a.u;
    return (u + 0x7FFFu + ((u >> 16) & 1u)) >> 16;
}
__device__ __forceinline__ unsigned pack2(float a, float b) {
    return f2bf(a) | (f2bf(b) << 16);
}
__device__ __forceinline__ float bf_lo(unsigned v) { return __uint_as_float(v << 16); }
__device__ __forceinline__ float bf_hi(unsigned v) { return __uint_as_float(v & 0xFFFF0000u); }

#define ACC4(a, u) { a[0]+=bf_lo(u.x); a[1]+=bf_hi(u.x); a[2]+=bf_lo(u.y); a[3]+=bf_hi(u.y); \
                     a[4]+=bf_lo(u.z); a[5]+=bf_hi(u.z); a[6]+=bf_lo(u.w); a[7]+=bf_hi(u.w); }

// ===========================================================================
// prep: fused conv_x (xb 128B bf16 rows + Acat x-part) | passA (per-tile
// bucket histogram) | conv_w (transposed bf16 weights).
// ===========================================================================
__global__ __launch_bounds__(256) void prep_kernel(
    const float* __restrict__ x,
    const int*   __restrict__ dst,
    const float* __restrict__ W1l, const float* __restrict__ W1r,
    const float* __restrict__ W2l, const float* __restrict__ W2r,
    unsigned* __restrict__ xb, unsigned* __restrict__ acat,
    int* __restrict__ g_hist,
    unsigned* __restrict__ Wt1g, unsigned* __restrict__ W2tg)
{
    __shared__ int lh[NB];
    int blk = blockIdx.x;
    int tid = threadIdx.x;

    if (blk < PREP_CONVX_BLOCKS) {
        // ---- conv_x: xb rows padded to 32 dwords (128B, 2 aligned lines) ----
        int t = blk * 256 + tid;
        int n = t >> 5, j = t & 31;
        if (j < 25) {
            float2 v = ((const float2*)x)[n * 25 + j];
            unsigned pk = pack2(v.x, v.y);
            xb[n * 32 + j] = pk;
            acat[(size_t)n * 64 + 25 + j] = pk;
        } else {
            xb[n * 32 + j] = 0u;
            int z = n * 64 + 50 + (j - 25) * 2;
            acat[z] = 0u;
            acat[z + 1] = 0u;
        }
    } else if (blk < PREP_CONVX_BLOCKS + NTILES) {
        // ---- passA: per-tile bucket histogram ----
        int tile = blk - PREP_CONVX_BLOCKS;
        for (int i = tid; i < NB; i += 256) lh[i] = 0;
        __syncthreads();
        int base = tile * TILE;
        int cnt = min(TILE, N_EDGES - base);
        for (int i = tid; i < cnt; i += 256)
            atomicAdd(&lh[dst[base + i] >> BSHIFT], 1);
        __syncthreads();
        for (int i = tid; i < NB; i += 256)
            g_hist[tile * NB + i] = lh[i];
    } else {
        // ---- conv_w ----
        int t = (blk - PREP_CONVX_BLOCKS - NTILES) * 256 + tid;
        if (t < 8192) {
            int n = t >> 6, kp = t & 63;
            int k0 = kp * 2, k1 = k0 + 1;
            float v0 = (k0 < 50) ? W1l[k0 * 128 + n] : ((k0 < 100) ? W1r[(k0 - 50) * 128 + n] : 0.0f);
            float v1 = (k1 < 50) ? W1l[k1 * 128 + n] : ((k1 < 100) ? W1r[(k1 - 50) * 128 + n] : 0.0f);
            Wt1g[t] = pack2(v0, v1);
        } else if (t < 8192 + 1024) {
            int u = t - 8192;
            int n2 = u >> 6, kp = u & 63;
            int k0 = kp * 2;
            float v0 = (n2 < 8) ? W2l[k0 * 8 + n2] : W2r[k0 * 8 + n2 - 8];
            float v1 = (n2 < 8) ? W2l[(k0 + 1) * 8 + n2] : W2r[(k0 + 1) * 8 + n2 - 8];
            W2tg[u] = pack2(v0, v1);
        }
    }
}

// ===========================================================================
// passB: per-bucket exclusive scan of g_hist over 782 tiles (2 per thread);
// writes bucket total to btot[b] (plain store, no pre-zero needed).
// ===========================================================================
__global__ __launch_bounds__(512) void passB_kernel(
    int* __restrict__ g_hist, int* __restrict__ btot)
{
    __shared__ int s[512];
    int b = blockIdx.x, tid = threadIdx.x;
    int t0 = 2 * tid, t1 = 2 * tid + 1;
    int v0 = (t0 < NTILES) ? g_hist[t0 * NB + b] : 0;
    int v1 = (t1 < NTILES) ? g_hist[t1 * NB + b] : 0;
    int v = v0 + v1;
    s[tid] = v;
    __syncthreads();
    for (int d = 1; d < 512; d <<= 1) {
        int t = (tid >= d) ? s[tid - d] : 0;
        __syncthreads();
        s[tid] += t;
        __syncthreads();
    }
    int ex = s[tid] - v;
    if (t0 < NTILES) g_hist[t0 * NB + b] = ex;
    if (t1 < NTILES) g_hist[t1 * NB + b] = ex + v0;
    if (tid == 511) btot[b] = s[511];
}

// ===========================================================================
// passC: reorder tile (2048 edges) by bucket in LDS; flush PACKED edges
// (src bits 0..16, dst_local bits 17..25) to bk_pack.
// bbase recomputed locally from btot (196-elem LDS scan) - no passB2 kernel.
// ===========================================================================
__global__ __launch_bounds__(256) void passC_kernel(
    const int* __restrict__ src, const int* __restrict__ dst,
    const int* __restrict__ g_hist, const int* __restrict__ btot,
    unsigned* __restrict__ bk_pack)
{
    __shared__ int hist[NB];
    __shared__ int seg[NB];
    __shared__ int cur[NB];
    __shared__ int gof[NB];
    __shared__ int sc[256];
    __shared__ unsigned s_pack[TILE];
    __shared__ unsigned short s_bkt[TILE];

    int tid = threadIdx.x, tile = blockIdx.x;
    int base = tile * TILE;
    int cnt = min(TILE, N_EDGES - base);

    // local bbase (exclusive scan of btot) folded into gof
    {
        int vb = (tid < NB) ? btot[tid] : 0;
        sc[tid] = vb;
        __syncthreads();
        for (int d = 1; d < 256; d <<= 1) {
            int t = (tid >= d) ? sc[tid - d] : 0;
            __syncthreads();
            sc[tid] += t;
            __syncthreads();
        }
        if (tid < NB) gof[tid] = g_hist[tile * NB + tid] + (sc[tid] - vb);
    }
    for (int i = tid; i < NB; i += 256) hist[i] = 0;
    __syncthreads();

    int es[8], ed[8];
    #pragma unroll
    for (int k = 0; k < 8; ++k) {
        int i = tid + k * 256;
        if (i < cnt) {
            es[k] = src[base + i];
            ed[k] = dst[base + i];
            atomicAdd(&hist[ed[k] >> BSHIFT], 1);
        }
    }
    __syncthreads();

    {
        int v = (tid < NB) ? hist[tid] : 0;
        sc[tid] = v;
        __syncthreads();
        for (int d = 1; d < 256; d <<= 1) {
            int t = (tid >= d) ? sc[tid - d] : 0;
            __syncthreads();
            sc[tid] += t;
            __syncthreads();
        }
        if (tid < NB) { seg[tid] = sc[tid] - v; cur[tid] = sc[tid] - v; }
    }
    __syncthreads();

    #pragma unroll
    for (int k = 0; k < 8; ++k) {
        int i = tid + k * 256;
        if (i < cnt) {
            int b = ed[k] >> BSHIFT;
            int p = atomicAdd(&cur[b], 1);
            s_pack[p] = (unsigned)es[k] | ((unsigned)(ed[k] & 511) << 17);
            s_bkt[p] = (unsigned short)b;
        }
    }
    __syncthreads();

    for (int i = tid; i < cnt; i += 256) {
        int b = s_bkt[i];
        int g = gof[b] + (i - seg[b]);
        bk_pack[g] = s_pack[i];
    }
}

// ===========================================================================
// passD: per-bucket CSR finalize from packed edges.
// bbase[b] recomputed locally from btot - no passB2 kernel.
// ===========================================================================
__global__ __launch_bounds__(512) void passD_kernel(
    const unsigned* __restrict__ bk_pack,
    const int* __restrict__ btot,
    int* __restrict__ sorted_src, int* __restrict__ offs)
{
    __shared__ int ldeg[512];
    __shared__ int lofs[512];
    __shared__ int shr[1];
    int b = blockIdx.x, tid = threadIdx.x;

    // local bbase[b] = exclusive prefix of btot at b (512-thread scan over 196)
    {
        int vb = (tid < NB) ? btot[tid] : 0;
        lofs[tid] = vb;
        __syncthreads();
        for (int d = 1; d < 512; d <<= 1) {
            int t = (tid >= d) ? lofs[tid - d] : 0;
            __syncthreads();
            lofs[tid] += t;
            __syncthreads();
        }
        if (tid == b) shr[0] = lofs[tid] - vb;
    }
    __syncthreads();
    int ebase = shr[0];
    int ecnt = btot[b];
    int nbase = b << BSHIFT;

    ldeg[tid] = 0;
    __syncthreads();
    for (int i = tid; i < ecnt; i += 512)
        atomicAdd(&ldeg[bk_pack[ebase + i] >> 17], 1);
    __syncthreads();

    int v = ldeg[tid];
    lofs[tid] = v;
    __syncthreads();
    for (int d = 1; d < 512; d <<= 1) {
        int t = (tid >= d) ? lofs[tid - d] : 0;
        __syncthreads();
        lofs[tid] += t;
        __syncthreads();
    }
    int ex = lofs[tid] - v;

    int node = nbase + tid;
    if (node < N_NODES) offs[node] = ebase + ex;

    ldeg[tid] = ex;
    __syncthreads();
    for (int i = tid; i < ecnt; i += 512) {
        unsigned pk = bk_pack[ebase + i];
        int p = atomicAdd(&ldeg[pk >> 17], 1);
        sorted_src[ebase + p] = (int)(pk & 0x1FFFFu);
    }
    if (b == 0 && tid == 0) offs[N_NODES] = N_EDGES;
}

// ===========================================================================
// Gather-aggregate bf16 x rows (128B rows, uint4 loads).
// ONE NODE PER WAVE: 8 edge-slots x 8 uint4-lanes, unroll 2 ->
// 16 edges in flight, zero intra-wave divergence.
// ===========================================================================
__global__ __launch_bounds__(256) void agg_x_kernel(
    const uint4* __restrict__ xb4,     // [N][8] uint4
    const int*   __restrict__ offs,
    const int*   __restrict__ ss,
    unsigned* __restrict__ acat)
{
    int node = blockIdx.x * 4 + (threadIdx.x >> 6);
    int lane = threadIdx.x & 63;
    int slot = lane >> 3;     // 0..7 (edge slot)
    int ld   = lane & 7;      // 0..7 (uint4 within 128B row)
    if (node >= N_NODES) return;
    int beg = offs[node], end = offs[node + 1];
    float a0[8] = {0,0,0,0,0,0,0,0};
    float a1[8] = {0,0,0,0,0,0,0,0};
    int i = beg;
    for (; i + 15 < end; i += 16) {
        int s0 = ss[i + slot];
        int s1 = ss[i + slot + 8];
        uint4 u0 = xb4[s0 * 8 + ld];
        uint4 u1 = xb4[s1 * 8 + ld];
        ACC4(a0, u0);
        ACC4(a1, u1);
    }
    for (; i + 7 < end; i += 8) {
        uint4 u = xb4[ss[i + slot] * 8 + ld];
        ACC4(a0, u);
    }
    int rem = end - i;
    if (slot < rem) {
        uint4 u = xb4[ss[i + slot] * 8 + ld];
        ACC4(a1, u);
    }
    float t[8];
    #pragma unroll
    for (int k = 0; k < 8; ++k) {
        float v = a0[k] + a1[k];
        v += __shfl_xor(v, 8);
        v += __shfl_xor(v, 16);
        v += __shfl_xor(v, 32);
        t[k] = v;
    }
    if (slot == 0) {
        float inv = 1.0f / fmaxf((float)(end - beg), 1.0f);
        if (ld < 6) {
            uint4 o;
            o.x = pack2(t[0] * inv, t[1] * inv);
            o.y = pack2(t[2] * inv, t[3] * inv);
            o.z = pack2(t[4] * inv, t[5] * inv);
            o.w = pack2(t[6] * inv, t[7] * inv);
            *((uint4*)(acat + (size_t)node * 64 + ld * 4)) = o;
        } else if (ld == 6) {
            acat[(size_t)node * 64 + 24] = pack2(t[0] * inv, t[1] * inv);
        }
    }
}

// ===========================================================================
// Fused MLP: h = relu(Acat @ W1cat + b1) via MFMA (swapped operands), then
// p = bf16(h@W2l), q = h@W2r + b2 via a second MFMA pass through LDS.
// ===========================================================================
__global__ __launch_bounds__(256) void fused_mlp_kernel(
    const unsigned* __restrict__ Acat,   // [N][64] dwords (128 bf16)
    const unsigned* __restrict__ Wt1g,   // [128][64] dwords
    const unsigned* __restrict__ W2tg,   // [16][64] dwords
    const float* __restrict__ b1,
    const float* __restrict__ b2,
    unsigned* __restrict__ pb,           // [N][4] dwords (8 bf16)
    float* __restrict__ q)               // [N][8]
{
    __shared__ unsigned sWt[128 * LW];
    __shared__ unsigned sW2t[16 * LW];
    __shared__ bf16_t   sH[4][16 * 136];

    int tid = threadIdx.x;
    for (int t = tid; t < 128 * 64; t += 256)
        sWt[(t >> 6) * LW + (t & 63)] = Wt1g[t];
    for (int t = tid; t < 16 * 64; t += 256)
        sW2t[(t >> 6) * LW + (t & 63)] = W2tg[t];
    __syncthreads();

    const int w    = tid >> 6;
    const int lane = tid & 63;
    const int lo   = lane & 15;
    const int g    = lane >> 4;

    float b1v[8][4];
    #pragma unroll
    for (int nt = 0; nt < 8; ++nt)
        #pragma unroll
        for (int r = 0; r < 4; ++r)
            b1v[nt][r] = b1[nt * 16 + g * 4 + r];
    float b2v[4];
    #pragma unroll
    for (int r = 0; r < 4; ++r)
        b2v[r] = (g >= 2) ? b2[(g - 2) * 4 + r] : 0.0f;

    bf16_t* myH = &sH[w][0];

    for (int tile = blockIdx.x; tile * 64 < N_NODES; tile += gridDim.x) {
        int node = tile * 64 + w * 16 + lo;
        int nclamp = min(node, N_NODES - 1);

        int4 bi[4];
        #pragma unroll
        for (int ks = 0; ks < 4; ++ks)
            bi[ks] = *((const int4*)(Acat + (size_t)nclamp * 64 + ks * 16 + g * 4));

        f32x4 acc[8];
        #pragma unroll
        for (int nt = 0; nt < 8; ++nt) acc[nt] = (f32x4)0.0f;
        #pragma unroll
        for (int nt = 0; nt < 8; ++nt) {
            #pragma unroll
            for (int ks = 0; ks < 4; ++ks) {
                int4 ai = *((const int4*)(sWt + (nt * 16 + lo) * LW + ks * 16 + g * 4));
                acc[nt] = __builtin_amdgcn_mfma_f32_16x16x32_bf16(
                    __builtin_bit_cast(bf16x8, ai),
                    __builtin_bit_cast(bf16x8, bi[ks]), acc[nt], 0, 0, 0);
            }
        }

        #pragma unroll
        for (int nt = 0; nt < 8; ++nt) {
            union { bf16_t h[4]; uint2 u; } pk;
            #pragma unroll
            for (int r = 0; r < 4; ++r)
                pk.h[r] = (bf16_t)fmaxf(acc[nt][r] + b1v[nt][r], 0.0f);
            *((uint2*)(myH + lo * 136 + nt * 16 + g * 4)) = pk.u;
        }
        __syncthreads();

        f32x4 acc2 = (f32x4)0.0f;
        #pragma unroll
        for (int ks = 0; ks < 4; ++ks) {
            int4 a2 = *((const int4*)(sW2t + lo * LW + ks * 16 + g * 4));
            int4 h2 = *((const int4*)(myH + lo * 136 + ks * 32 + g * 8));
            acc2 = __builtin_amdgcn_mfma_f32_16x16x32_bf16(
                __builtin_bit_cast(bf16x8, a2),
                __builtin_bit_cast(bf16x8, h2), acc2, 0, 0, 0);
        }

        if (node < N_NODES) {
            if (g < 2) {
                union { bf16_t h[4]; uint2 u; } pk;
                #pragma unroll
                for (int r = 0; r < 4; ++r) pk.h[r] = (bf16_t)acc2[r];
                *((uint2*)(pb + (size_t)node * 4 + g * 2)) = pk.u;
            } else {
                float4 qq;
                qq.x = acc2[0] + b2v[0];
                qq.y = acc2[1] + b2v[1];
                qq.z = acc2[2] + b2v[2];
                qq.w = acc2[3] + b2v[3];
                *((float4*)(q + (size_t)node * 8 + (g - 2) * 4)) = qq;
            }
        }
        __syncthreads();
    }
}

// ===========================================================================
// Gather-aggregate bf16 p rows + final: out = (sum p[src]) / max(deg,1) + q
// ===========================================================================
__global__ __launch_bounds__(256) void aggp_final_kernel(
    const unsigned* __restrict__ pb,   // [N][4] dwords (8 bf16)
    const float*    __restrict__ q,
    const int*      __restrict__ offs,
    const int*      __restrict__ ss,
    float* __restrict__ out)
{
    int node = blockIdx.x * 4 + (threadIdx.x >> 6);
    int lane = threadIdx.x & 63;
    int k  = lane >> 2;
    int c2 = lane & 3;
    if (node >= N_NODES) return;
    int beg = offs[node], end = offs[node + 1];
    float2 acc = make_float2(0.0f, 0.0f);
    int i = beg + k;
    int sNext = (i < end) ? ss[i] : 0;
    for (; i < end; i += 16) {
        int s = sNext;
        int i2 = i + 16;
        sNext = (i2 < end) ? ss[i2] : 0;
        unsigned v = pb[s * 4 + c2];
        acc.x += bf_lo(v);
        acc.y += bf_hi(v);
    }
    acc.x += __shfl_xor(acc.x, 4);  acc.y += __shfl_xor(acc.y, 4);
    acc.x += __shfl_xor(acc.x, 8);  acc.y += __shfl_xor(acc.y, 8);
    acc.x += __shfl_xor(acc.x, 16); acc.y += __shfl_xor(acc.y, 16);
    acc.x += __shfl_xor(acc.x, 32); acc.y += __shfl_xor(acc.y, 32);
    if (lane < 4) {
        float inv = 1.0f / fmaxf((float)(end - beg), 1.0f);
        float2 qq = ((const float2*)(q + (size_t)node * NCLS))[c2];
        ((float2*)(out + (size_t)node * NCLS))[c2] =
            make_float2(acc.x * inv + qq.x, acc.y * inv + qq.y);
    }
}

// ===========================================================================
extern "C" void kernel_launch(void* const* d_in, const int* in_sizes, int n_in,
                              void* d_out, int out_size, void* d_ws, size_t ws_size,
                              hipStream_t stream)
{
    const float* x   = (const float*)d_in[0];
    const int*   ei  = (const int*)  d_in[1];
    const float* W1l = (const float*)d_in[2];
    const float* W1r = (const float*)d_in[3];
    const float* b1  = (const float*)d_in[4];
    const float* W2l = (const float*)d_in[5];
    const float* W2r = (const float*)d_in[6];
    const float* b2  = (const float*)d_in[7];
    float* out = (float*)d_out;

    const int* src = ei;
    const int* dst = ei + N_EDGES;

    // Workspace layout (dword units; all segment sizes are multiples of 4)
    int* ws = (int*)d_ws;
    int*      offs       = ws;                                   // 100004
    int*      g_hist     = offs + (N_NODES + 4);                 // NTILES*NB + pad
    int*      btot       = g_hist + (NTILES * NB + 4);           // 512
    int*      sorted_src = btot + 512;                           // E
    unsigned* xb         = (unsigned*)(sorted_src + N_EDGES);    // N*32 (128B rows)
    unsigned* Acat       = xb + (size_t)N_NODES * 32;            // N*64
    unsigned* Wt1g       = Acat + (size_t)N_NODES * 64;          // 8192
    unsigned* W2tg       = Wt1g + 8192;                          // 1024
    unsigned* pb         = W2tg + 1024;                          // N*4
    float*    q          = (float*)(pb + (size_t)N_NODES * 4);   // N*8
    unsigned* bk_pack    = (unsigned*)(q + (size_t)N_NODES * 8); // E

    // prep: conv_x | passA | conv_w fused
    prep_kernel<<<PREP_CONVX_BLOCKS + NTILES + PREP_W_BLOCKS, 256, 0, stream>>>(
        x, dst, W1l, W1r, W2l, W2r, xb, Acat, g_hist, Wt1g, W2tg);

    // CSR build (bbase recomputed locally in passC/passD; no passB2)
    passB_kernel<<<NB, 512, 0, stream>>>(g_hist, btot);
    passC_kernel<<<NTILES, 256, 0, stream>>>(src, dst, g_hist, btot, bk_pack);
    passD_kernel<<<NB, 512, 0, stream>>>(bk_pack, btot, sorted_src, offs);

    // Layer 1 aggregation (writes Acat cols 0..49)
    agg_x_kernel<<<(N_NODES + 3) / 4, 256, 0, stream>>>(
        (const uint4*)xb, offs, sorted_src, Acat);

    // Fused layer1 GEMM + relu + layer2 GEMMs (h stays on-chip)
    fused_mlp_kernel<<<512, 256, 0, stream>>>(Acat, Wt1g, W2tg, b1, b2, pb, q);

    // Layer 2 aggregation + final
    aggp_final_kernel<<<(N_NODES + 3) / 4, 256, 0, stream>>>(
        (const unsigned*)pb, q, offs, sorted_src, out);
}

// Round 15
// 123.549 us; speedup vs baseline: 3.0014x; 1.0246x over previous
//
#include <hip/hip_runtime.h>

// Problem constants (from reference)
#define N_NODES 100000
#define N_EDGES 1600000
#define D_IN    50
#define HIDDEN  128
#define NCLS    8

// Bucket-sort parameters
#define TILE    2048
#define NTILES  ((N_EDGES + TILE - 1) / TILE)   // 782
#define BSHIFT  9
#define NB      196                              // ceil(100000 / 512)

// prep kernel block ranges
#define PREP_CONVX_BLOCKS 12500                  // N_NODES*32 / 256
#define PREP_W_BLOCKS     36                     // 9216 threads

// LDS row stride (dwords) for padded bf16 weight rows: 128 bf16 + 8 pad = 136 bf16
#define LW 68

typedef __bf16 bf16_t;
typedef bf16_t bf16x8 __attribute__((ext_vector_type(8)));
typedef float  f32x4  __attribute__((ext_vector_type(4)));

// ---------------------------------------------------------------------------
// Helpers: bf16 pack/unpack (RNE)
// ---------------------------------------------------------------------------
__device__ __forceinline__ unsigned f2bf(float f) {
    union { float f; unsigned u; } a; a.f = f;
    unsigned u = a.u;
    return (u + 0x7FFFu + ((u >> 16) & 1u)) >> 16;
}
__device__ __forceinline__ unsigned pack2(float a, float b) {
    return f2bf(a) | (f2bf(b) << 16);
}
__device__ __forceinline__ float bf_lo(unsigned v) { return __uint_as_float(v << 16); }
__device__ __forceinline__ float bf_hi(unsigned v) { return __uint_as_float(v & 0xFFFF0000u); }

#define ACC4(a, u) { a[0]+=bf_lo(u.x); a[1]+=bf_hi(u.x); a[2]+=bf_lo(u.y); a[3]+=bf_hi(u.y); \
                     a[4]+=bf_lo(u.z); a[5]+=bf_hi(u.z); a[6]+=bf_lo(u.w); a[7]+=bf_hi(u.w); }

// ===========================================================================
// prep: fused conv_x (xb 128B bf16 rows, zero-padded) | passA (per-tile
// bucket histogram) | conv_w (transposed, K-split bf16 weights).
// W1cat^T row n, element k: k<50 -> W1l[k], 64<=k<114 -> W1r[k-64], else 0.
// ===========================================================================
__global__ __launch_bounds__(256) void prep_kernel(
    const float* __restrict__ x,
    const int*   __restrict__ dst,
    const float* __restrict__ W1l, const float* __restrict__ W1r,
    const float* __restrict__ W2l, const float* __restrict__ W2r,
    unsigned* __restrict__ xb,
    int* __restrict__ g_hist,
    unsigned* __restrict__ Wt1g, unsigned* __restrict__ W2tg)
{
    __shared__ int lh[NB];
    int blk = blockIdx.x;
    int tid = threadIdx.x;

    if (blk < PREP_CONVX_BLOCKS) {
        // ---- conv_x: xb rows padded to 32 dwords (128B, 2 aligned lines) ----
        int t = blk * 256 + tid;
        int n = t >> 5, j = t & 31;
        if (j < 25) {
            float2 v = ((const float2*)x)[n * 25 + j];
            xb[n * 32 + j] = pack2(v.x, v.y);
        } else {
            xb[n * 32 + j] = 0u;
        }
    } else if (blk < PREP_CONVX_BLOCKS + NTILES) {
        // ---- passA: per-tile bucket histogram ----
        int tile = blk - PREP_CONVX_BLOCKS;
        for (int i = tid; i < NB; i += 256) lh[i] = 0;
        __syncthreads();
        int base = tile * TILE;
        int cnt = min(TILE, N_EDGES - base);
        for (int i = tid; i < cnt; i += 256)
            atomicAdd(&lh[dst[base + i] >> BSHIFT], 1);
        __syncthreads();
        for (int i = tid; i < NB; i += 256)
            g_hist[tile * NB + i] = lh[i];
    } else {
        // ---- conv_w (K-split layout) ----
        int t = (blk - PREP_CONVX_BLOCKS - NTILES) * 256 + tid;
        if (t < 8192) {
            int n = t >> 6, kp = t & 63;
            int k0 = kp * 2, k1 = k0 + 1;
            float v0 = (k0 < 50) ? W1l[k0 * 128 + n]
                     : ((k0 >= 64 && k0 < 114) ? W1r[(k0 - 64) * 128 + n] : 0.0f);
            float v1 = (k1 < 50) ? W1l[k1 * 128 + n]
                     : ((k1 >= 64 && k1 < 114) ? W1r[(k1 - 64) * 128 + n] : 0.0f);
            Wt1g[t] = pack2(v0, v1);
        } else if (t < 8192 + 1024) {
            int u = t - 8192;
            int n2 = u >> 6, kp = u & 63;
            int k0 = kp * 2;
            float v0 = (n2 < 8) ? W2l[k0 * 8 + n2] : W2r[k0 * 8 + n2 - 8];
            float v1 = (n2 < 8) ? W2l[(k0 + 1) * 8 + n2] : W2r[(k0 + 1) * 8 + n2 - 8];
            W2tg[u] = pack2(v0, v1);
        }
    }
}

// ===========================================================================
// passB: per-bucket exclusive scan of g_hist over 782 tiles (2 per thread);
// writes bucket total to btot[b] (plain store, no pre-zero needed).
// ===========================================================================
__global__ __launch_bounds__(512) void passB_kernel(
    int* __restrict__ g_hist, int* __restrict__ btot)
{
    __shared__ int s[512];
    int b = blockIdx.x, tid = threadIdx.x;
    int t0 = 2 * tid, t1 = 2 * tid + 1;
    int v0 = (t0 < NTILES) ? g_hist[t0 * NB + b] : 0;
    int v1 = (t1 < NTILES) ? g_hist[t1 * NB + b] : 0;
    int v = v0 + v1;
    s[tid] = v;
    __syncthreads();
    for (int d = 1; d < 512; d <<= 1) {
        int t = (tid >= d) ? s[tid - d] : 0;
        __syncthreads();
        s[tid] += t;
        __syncthreads();
    }
    int ex = s[tid] - v;
    if (t0 < NTILES) g_hist[t0 * NB + b] = ex;
    if (t1 < NTILES) g_hist[t1 * NB + b] = ex + v0;
    if (tid == 511) btot[b] = s[511];
}

// ===========================================================================
// passC: reorder tile (2048 edges) by bucket in LDS; flush PACKED edges
// (src bits 0..16, dst_local bits 17..25) to bk_pack.
// bbase recomputed locally from btot (196-elem LDS scan).
// ===========================================================================
__global__ __launch_bounds__(256) void passC_kernel(
    const int* __restrict__ src, const int* __restrict__ dst,
    const int* __restrict__ g_hist, const int* __restrict__ btot,
    unsigned* __restrict__ bk_pack)
{
    __shared__ int hist[NB];
    __shared__ int seg[NB];
    __shared__ int cur[NB];
    __shared__ int gof[NB];
    __shared__ int sc[256];
    __shared__ unsigned s_pack[TILE];
    __shared__ unsigned short s_bkt[TILE];

    int tid = threadIdx.x, tile = blockIdx.x;
    int base = tile * TILE;
    int cnt = min(TILE, N_EDGES - base);

    // local bbase (exclusive scan of btot) folded into gof
    {
        int vb = (tid < NB) ? btot[tid] : 0;
        sc[tid] = vb;
        __syncthreads();
        for (int d = 1; d < 256; d <<= 1) {
            int t = (tid >= d) ? sc[tid - d] : 0;
            __syncthreads();
            sc[tid] += t;
            __syncthreads();
        }
        if (tid < NB) gof[tid] = g_hist[tile * NB + tid] + (sc[tid] - vb);
    }
    for (int i = tid; i < NB; i += 256) hist[i] = 0;
    __syncthreads();

    int es[8], ed[8];
    #pragma unroll
    for (int k = 0; k < 8; ++k) {
        int i = tid + k * 256;
        if (i < cnt) {
            es[k] = src[base + i];
            ed[k] = dst[base + i];
            atomicAdd(&hist[ed[k] >> BSHIFT], 1);
        }
    }
    __syncthreads();

    {
        int v = (tid < NB) ? hist[tid] : 0;
        sc[tid] = v;
        __syncthreads();
        for (int d = 1; d < 256; d <<= 1) {
            int t = (tid >= d) ? sc[tid - d] : 0;
            __syncthreads();
            sc[tid] += t;
            __syncthreads();
        }
        if (tid < NB) { seg[tid] = sc[tid] - v; cur[tid] = sc[tid] - v; }
    }
    __syncthreads();

    #pragma unroll
    for (int k = 0; k < 8; ++k) {
        int i = tid + k * 256;
        if (i < cnt) {
            int b = ed[k] >> BSHIFT;
            int p = atomicAdd(&cur[b], 1);
            s_pack[p] = (unsigned)es[k] | ((unsigned)(ed[k] & 511) << 17);
            s_bkt[p] = (unsigned short)b;
        }
    }
    __syncthreads();

    for (int i = tid; i < cnt; i += 256) {
        int b = s_bkt[i];
        int g = gof[b] + (i - seg[b]);
        bk_pack[g] = s_pack[i];
    }
}

// ===========================================================================
// passD: per-bucket CSR finalize from packed edges.
// bbase[b] recomputed locally from btot.
// ===========================================================================
__global__ __launch_bounds__(512) void passD_kernel(
    const unsigned* __restrict__ bk_pack,
    const int* __restrict__ btot,
    int* __restrict__ sorted_src, int* __restrict__ offs)
{
    __shared__ int ldeg[512];
    __shared__ int lofs[512];
    __shared__ int shr[1];
    int b = blockIdx.x, tid = threadIdx.x;

    {
        int vb = (tid < NB) ? btot[tid] : 0;
        lofs[tid] = vb;
        __syncthreads();
        for (int d = 1; d < 512; d <<= 1) {
            int t = (tid >= d) ? lofs[tid - d] : 0;
            __syncthreads();
            lofs[tid] += t;
            __syncthreads();
        }
        if (tid == b) shr[0] = lofs[tid] - vb;
    }
    __syncthreads();
    int ebase = shr[0];
    int ecnt = btot[b];
    int nbase = b << BSHIFT;

    ldeg[tid] = 0;
    __syncthreads();
    for (int i = tid; i < ecnt; i += 512)
        atomicAdd(&ldeg[bk_pack[ebase + i] >> 17], 1);
    __syncthreads();

    int v = ldeg[tid];
    lofs[tid] = v;
    __syncthreads();
    for (int d = 1; d < 512; d <<= 1) {
        int t = (tid >= d) ? lofs[tid - d] : 0;
        __syncthreads();
        lofs[tid] += t;
        __syncthreads();
    }
    int ex = lofs[tid] - v;

    int node = nbase + tid;
    if (node < N_NODES) offs[node] = ebase + ex;

    ldeg[tid] = ex;
    __syncthreads();
    for (int i = tid; i < ecnt; i += 512) {
        unsigned pk = bk_pack[ebase + i];
        int p = atomicAdd(&ldeg[pk >> 17], 1);
        sorted_src[ebase + p] = (int)(pk & 0x1FFFFu);
    }
    if (b == 0 && tid == 0) offs[N_NODES] = N_EDGES;
}

// ===========================================================================
// Gather-aggregate bf16 x rows (128B rows, uint4 loads).
// ONE NODE PER WAVE: 8 edge-slots x 8 uint4-lanes, unroll 2.
// Writes FULL 128B padded rows to am (pads are zero because xb pads are).
// ===========================================================================
__global__ __launch_bounds__(256) void agg_x_kernel(
    const uint4* __restrict__ xb4,     // [N][8] uint4
    const int*   __restrict__ offs,
    const int*   __restrict__ ss,
    unsigned* __restrict__ am)         // [N][32] dwords
{
    int node = blockIdx.x * 4 + (threadIdx.x >> 6);
    int lane = threadIdx.x & 63;
    int slot = lane >> 3;     // 0..7 (edge slot)
    int ld   = lane & 7;      // 0..7 (uint4 within 128B row)
    if (node >= N_NODES) return;
    int beg = offs[node], end = offs[node + 1];
    float a0[8] = {0,0,0,0,0,0,0,0};
    float a1[8] = {0,0,0,0,0,0,0,0};
    int i = beg;
    for (; i + 15 < end; i += 16) {
        int s0 = ss[i + slot];
        int s1 = ss[i + slot + 8];
        uint4 u0 = xb4[s0 * 8 + ld];
        uint4 u1 = xb4[s1 * 8 + ld];
        ACC4(a0, u0);
        ACC4(a1, u1);
    }
    for (; i + 7 < end; i += 8) {
        uint4 u = xb4[ss[i + slot] * 8 + ld];
        ACC4(a0, u);
    }
    int rem = end - i;
    if (slot < rem) {
        uint4 u = xb4[ss[i + slot] * 8 + ld];
        ACC4(a1, u);
    }
    float t[8];
    #pragma unroll
    for (int k = 0; k < 8; ++k) {
        float v = a0[k] + a1[k];
        v += __shfl_xor(v, 8);
        v += __shfl_xor(v, 16);
        v += __shfl_xor(v, 32);
        t[k] = v;
    }
    if (slot == 0) {
        float inv = 1.0f / fmaxf((float)(end - beg), 1.0f);
        uint4 o;
        o.x = pack2(t[0] * inv, t[1] * inv);
        o.y = pack2(t[2] * inv, t[3] * inv);
        o.z = pack2(t[4] * inv, t[5] * inv);
        o.w = pack2(t[6] * inv, t[7] * inv);
        *((uint4*)(am + (size_t)node * 32 + ld * 4)) = o;
    }
}

// ===========================================================================
// Fused MLP: h = relu([am|xb] @ W1cat + b1) via MFMA (swapped operands),
// then p = bf16(h@W2l), q = h@W2r + b2 via a second MFMA pass through LDS.
// K-split: ks 0-1 read am rows, ks 2-3 read xb rows (both [N][32] dwords).
// ===========================================================================
__global__ __launch_bounds__(256) void fused_mlp_kernel(
    const unsigned* __restrict__ am,     // [N][32] dwords (64 bf16: aggm+pad)
    const unsigned* __restrict__ xb,     // [N][32] dwords (64 bf16: x+pad)
    const unsigned* __restrict__ Wt1g,   // [128][64] dwords
    const unsigned* __restrict__ W2tg,   // [16][64] dwords
    const float* __restrict__ b1,
    const float* __restrict__ b2,
    unsigned* __restrict__ pb,           // [N][4] dwords (8 bf16)
    float* __restrict__ q)               // [N][8]
{
    __shared__ unsigned sWt[128 * LW];
    __shared__ unsigned sW2t[16 * LW];
    __shared__ bf16_t   sH[4][16 * 136];

    int tid = threadIdx.x;
    for (int t = tid; t < 128 * 64; t += 256)
        sWt[(t >> 6) * LW + (t & 63)] = Wt1g[t];
    for (int t = tid; t < 16 * 64; t += 256)
        sW2t[(t >> 6) * LW + (t & 63)] = W2tg[t];
    __syncthreads();

    const int w    = tid >> 6;
    const int lane = tid & 63;
    const int lo   = lane & 15;
    const int g    = lane >> 4;

    float b1v[8][4];
    #pragma unroll
    for (int nt = 0; nt < 8; ++nt)
        #pragma unroll
        for (int r = 0; r < 4; ++r)
            b1v[nt][r] = b1[nt * 16 + g * 4 + r];
    float b2v[4];
    #pragma unroll
    for (int r = 0; r < 4; ++r)
        b2v[r] = (g >= 2) ? b2[(g - 2) * 4 + r] : 0.0f;

    bf16_t* myH = &sH[w][0];

    for (int tile = blockIdx.x; tile * 64 < N_NODES; tile += gridDim.x) {
        int node = tile * 64 + w * 16 + lo;
        int nclamp = min(node, N_NODES - 1);

        int4 bi[4];
        bi[0] = *((const int4*)(am + (size_t)nclamp * 32 + g * 4));
        bi[1] = *((const int4*)(am + (size_t)nclamp * 32 + 16 + g * 4));
        bi[2] = *((const int4*)(xb + (size_t)nclamp * 32 + g * 4));
        bi[3] = *((const int4*)(xb + (size_t)nclamp * 32 + 16 + g * 4));

        f32x4 acc[8];
        #pragma unroll
        for (int nt = 0; nt < 8; ++nt) acc[nt] = (f32x4)0.0f;
        #pragma unroll
        for (int nt = 0; nt < 8; ++nt) {
            #pragma unroll
            for (int ks = 0; ks < 4; ++ks) {
                int4 ai = *((const int4*)(sWt + (nt * 16 + lo) * LW + ks * 16 + g * 4));
                acc[nt] = __builtin_amdgcn_mfma_f32_16x16x32_bf16(
                    __builtin_bit_cast(bf16x8, ai),
                    __builtin_bit_cast(bf16x8, bi[ks]), acc[nt], 0, 0, 0);
            }
        }

        #pragma unroll
        for (int nt = 0; nt < 8; ++nt) {
            union { bf16_t h[4]; uint2 u; } pk;
            #pragma unroll
            for (int r = 0; r < 4; ++r)
                pk.h[r] = (bf16_t)fmaxf(acc[nt][r] + b1v[nt][r], 0.0f);
            *((uint2*)(myH + lo * 136 + nt * 16 + g * 4)) = pk.u;
        }
        __syncthreads();

        f32x4 acc2 = (f32x4)0.0f;
        #pragma unroll
        for (int ks = 0; ks < 4; ++ks) {
            int4 a2 = *((const int4*)(sW2t + lo * LW + ks * 16 + g * 4));
            int4 h2 = *((const int4*)(myH + lo * 136 + ks * 32 + g * 8));
            acc2 = __builtin_amdgcn_mfma_f32_16x16x32_bf16(
                __builtin_bit_cast(bf16x8, a2),
                __builtin_bit_cast(bf16x8, h2), acc2, 0, 0, 0);
        }

        if (node < N_NODES) {
            if (g < 2) {
                union { bf16_t h[4]; uint2 u; } pk;
                #pragma unroll
                for (int r = 0; r < 4; ++r) pk.h[r] = (bf16_t)acc2[r];
                *((uint2*)(pb + (size_t)node * 4 + g * 2)) = pk.u;
            } else {
                float4 qq;
                qq.x = acc2[0] + b2v[0];
                qq.y = acc2[1] + b2v[1];
                qq.z = acc2[2] + b2v[2];
                qq.w = acc2[3] + b2v[3];
                *((float4*)(q + (size_t)node * 8 + (g - 2) * 4)) = qq;
            }
        }
        __syncthreads();
    }
}

// ===========================================================================
// Gather-aggregate bf16 p rows + final: out = (sum p[src]) / max(deg,1) + q
// ===========================================================================
__global__ __launch_bounds__(256) void aggp_final_kernel(
    const unsigned* __restrict__ pb,   // [N][4] dwords (8 bf16)
    const float*    __restrict__ q,
    const int*      __restrict__ offs,
    const int*      __restrict__ ss,
    float* __restrict__ out)
{
    int node = blockIdx.x * 4 + (threadIdx.x >> 6);
    int lane = threadIdx.x & 63;
    int k  = lane >> 2;
    int c2 = lane & 3;
    if (node >= N_NODES) return;
    int beg = offs[node], end = offs[node + 1];
    float2 acc = make_float2(0.0f, 0.0f);
    int i = beg + k;
    int sNext = (i < end) ? ss[i] : 0;
    for (; i < end; i += 16) {
        int s = sNext;
        int i2 = i + 16;
        sNext = (i2 < end) ? ss[i2] : 0;
        unsigned v = pb[s * 4 + c2];
        acc.x += bf_lo(v);
        acc.y += bf_hi(v);
    }
    acc.x += __shfl_xor(acc.x, 4);  acc.y += __shfl_xor(acc.y, 4);
    acc.x += __shfl_xor(acc.x, 8);  acc.y += __shfl_xor(acc.y, 8);
    acc.x += __shfl_xor(acc.x, 16); acc.y += __shfl_xor(acc.y, 16);
    acc.x += __shfl_xor(acc.x, 32); acc.y += __shfl_xor(acc.y, 32);
    if (lane < 4) {
        float inv = 1.0f / fmaxf((float)(end - beg), 1.0f);
        float2 qq = ((const float2*)(q + (size_t)node * NCLS))[c2];
        ((float2*)(out + (size_t)node * NCLS))[c2] =
            make_float2(acc.x * inv + qq.x, acc.y * inv + qq.y);
    }
}

// ===========================================================================
extern "C" void kernel_launch(void* const* d_in, const int* in_sizes, int n_in,
                              void* d_out, int out_size, void* d_ws, size_t ws_size,
                              hipStream_t stream)
{
    const float* x   = (const float*)d_in[0];
    const int*   ei  = (const int*)  d_in[1];
    const float* W1l = (const float*)d_in[2];
    const float* W1r = (const float*)d_in[3];
    const float* b1  = (const float*)d_in[4];
    const float* W2l = (const float*)d_in[5];
    const float* W2r = (const float*)d_in[6];
    const float* b2  = (const float*)d_in[7];
    float* out = (float*)d_out;

    const int* src = ei;
    const int* dst = ei + N_EDGES;

    // Workspace layout (dword units; all segment sizes are multiples of 4)
    int* ws = (int*)d_ws;
    int*      offs       = ws;                                   // 100004
    int*      g_hist     = offs + (N_NODES + 4);                 // NTILES*NB + pad
    int*      btot       = g_hist + (NTILES * NB + 4);           // 512
    int*      sorted_src = btot + 512;                           // E
    unsigned* xb         = (unsigned*)(sorted_src + N_EDGES);    // N*32 (128B rows)
    unsigned* am         = xb + (size_t)N_NODES * 32;            // N*32 (128B rows)
    unsigned* Wt1g       = am + (size_t)N_NODES * 32;            // 8192
    unsigned* W2tg       = Wt1g + 8192;                          // 1024
    unsigned* pb         = W2tg + 1024;                          // N*4
    float*    q          = (float*)(pb + (size_t)N_NODES * 4);   // N*8
    unsigned* bk_pack    = (unsigned*)(q + (size_t)N_NODES * 8); // E

    // prep: conv_x | passA | conv_w fused
    prep_kernel<<<PREP_CONVX_BLOCKS + NTILES + PREP_W_BLOCKS, 256, 0, stream>>>(
        x, dst, W1l, W1r, W2l, W2r, xb, g_hist, Wt1g, W2tg);

    // CSR build
    passB_kernel<<<NB, 512, 0, stream>>>(g_hist, btot);
    passC_kernel<<<NTILES, 256, 0, stream>>>(src, dst, g_hist, btot, bk_pack);
    passD_kernel<<<NB, 512, 0, stream>>>(bk_pack, btot, sorted_src, offs);

    // Layer 1 aggregation (writes full padded am rows)
    agg_x_kernel<<<(N_NODES + 3) / 4, 256, 0, stream>>>(
        (const uint4*)xb, offs, sorted_src, am);

    // Fused layer1 GEMM + relu + layer2 GEMMs (h stays on-chip)
    fused_mlp_kernel<<<512, 256, 0, stream>>>(am, xb, Wt1g, W2tg, b1, b2, pb, q);

    // Layer 2 aggregation + final
    aggp_final_kernel<<<(N_NODES + 3) / 4, 256, 0, stream>>>(
        (const unsigned*)pb, q, offs, sorted_src, out);
}